// Round 8
// baseline (620.675 us; speedup 1.0000x reference)
//
#include <hip/hip_runtime.h>

typedef unsigned short u16;
typedef __attribute__((ext_vector_type(8))) short short8;
typedef __attribute__((ext_vector_type(4))) float floatx4;

#define NN 50000
#define NE 1600000
#define BN_EPS 1e-5f
#define TPB 8                 // 16-edge tiles per k_edge8 block

// LDS-only barrier: drains lgkmcnt (DS ops) but NOT vmcnt.
#define LDS_BARRIER() asm volatile("s_waitcnt lgkmcnt(0)\n\ts_barrier" ::: "memory")

__device__ __forceinline__ float bfu(u16 u) {
    union { unsigned u32; float f; } v; v.u32 = ((unsigned)u) << 16; return v.f;
}
__device__ __forceinline__ u16 f2bf(float f) {
    union { float f; unsigned u; } v; v.f = f;
    unsigned r = v.u + 0x7FFFu + ((v.u >> 16) & 1u);
    return (u16)(r >> 16);
}
// mode m: 1 = buffers hold float32, 0 = buffers hold bf16
__device__ __forceinline__ float ldf(const void* p, int i, int m) {
    return m ? ((const float*)p)[i] : bfu(((const u16*)p)[i]);
}

// K0b: canonicalize all MFMA-consumed weights to bf16 ws copies, with INLINE dtype
// detection (every block recomputes mode from x; block 0 publishes it). Block 256
// computes the PN rank-1 vectors instead of converting weights.
// Layout in dst: Wfe0[16384] | We1[8192] | Wfn0[16384] | Wn1[8192] | Wfn1[16384]
__global__ __launch_bounds__(256) void k_cvtw(const u16* __restrict__ x,
                                              const void* __restrict__ W0, const void* __restrict__ W1,
                                              const void* __restrict__ W2, const void* __restrict__ W3,
                                              const void* __restrict__ W4,
                                              const void* __restrict__ We0raw,
                                              u16* __restrict__ dst, float* __restrict__ PN,
                                              int* __restrict__ mode) {
    int t = threadIdx.x;
    __shared__ float sred[4];
    float mx = 0.f;
    for (int i = t; i < 4096; i += 256) mx = fmaxf(mx, fabsf(bfu(x[i])));
#pragma unroll
    for (int o = 32; o > 0; o >>= 1) mx = fmaxf(mx, __shfl_down(mx, o));
    if ((t & 63) == 0) sred[t >> 6] = mx;
    __syncthreads();
    float m2 = fmaxf(fmaxf(sred[0], sred[1]), fmaxf(sred[2], sred[3]));
    int m = (m2 > 1e4f) ? 1 : 0;
    if (blockIdx.x == 0 && t == 0) mode[0] = m;
    if (blockIdx.x == 256) {   // PN block: P[j]/N[j] from raw We0 + raw Wfe0 (W0)
        if (t < 128) {
            float p = 0.f, n = 0.f;
            for (int k = 0; k < 64; k++) {
                float w = ldf(We0raw, k, m);
                float wf = ldf(W0, t * 128 + 64 + k, m);
                p += fmaxf(w, 0.f) * wf;
                n += fminf(w, 0.f) * wf;
            }
            PN[t] = p; PN[128 + t] = n;
        }
        return;
    }
    int i = blockIdx.x * 256 + t;   // 65536 total
    const void* src; int off;
    if (i < 16384)      { src = W0; off = i; }
    else if (i < 24576) { src = W1; off = i - 16384; }
    else if (i < 40960) { src = W2; off = i - 24576; }
    else if (i < 49152) { src = W3; off = i - 40960; }
    else                { src = W4; off = i - 49152; }
    dst[i] = m ? f2bf(((const float*)src)[off]) : ((const u16*)src)[off];
}

// K1h: fused {node encoder l0 (16 nodes/block)} + {per-node +/- edge_attr sums} via block split.
__global__ __launch_bounds__(256) void k_enc0h(const void* __restrict__ x, const void* __restrict__ Wn,
                                               u16* __restrict__ n1, const int* __restrict__ ei,
                                               const void* __restrict__ ea,
                                               float* __restrict__ sp, float* __restrict__ sn,
                                               const int* __restrict__ mf) {
    int b = blockIdx.x;
    int t = threadIdx.x;
    int m = mf[0];
    if (b >= 3125) {   // esum part: 6250 blocks
        int e = (b - 3125) * 256 + t;
        float a = ldf(ea, e, m);
        int d = ei[NE + e];
        if (a > 0.f) atomicAdd(sp + d, a);
        else if (a < 0.f) atomicAdd(sn + d, a);
        return;
    }
    __shared__ float Wns[64 * 17];
    __shared__ float xsh[16][17];
    int n0 = b * 16;
    for (int i = t; i < 1024; i += 256) Wns[(i >> 4) * 17 + (i & 15)] = ldf(Wn, i, m);
    xsh[t >> 4][t & 15] = ldf(x, n0 * 16 + t, m);
    __syncthreads();
    int c = t & 63, ng = t >> 6;   // ng: node group 0..3, nodes ng*4..ng*4+3
    float a0 = 0.f, a1 = 0.f, a2 = 0.f, a3 = 0.f;
#pragma unroll
    for (int k = 0; k < 16; k++) {
        float wv = Wns[c * 17 + k];
        a0 += xsh[ng * 4 + 0][k] * wv;
        a1 += xsh[ng * 4 + 1][k] * wv;
        a2 += xsh[ng * 4 + 2][k] * wv;
        a3 += xsh[ng * 4 + 3][k] * wv;
    }
    n1[(n0 + ng * 4 + 0) * 64 + c] = f2bf(fmaxf(a0, 0.f));
    n1[(n0 + ng * 4 + 1) * 64 + c] = f2bf(fmaxf(a1, 0.f));
    n1[(n0 + ng * 4 + 2) * 64 + c] = f2bf(fmaxf(a2, 0.f));
    n1[(n0 + ng * 4 + 3) * 64 + c] = f2bf(fmaxf(a3, 0.f));
}

// K_Z: per-node edge-MLP precompute. z[n][j] = sum_k n1l0[n][k]*Wfe0[j][k] + 0.5*bfe0[j]
// (j=0..127; Wfe0 cols 0..63 = node part). Then for any edge: h1 = relu(z[s]+z[d]+ae*PN).
__global__ __launch_bounds__(256) void k_z(const u16* __restrict__ n1l0, const u16* __restrict__ Wfe0c,
                                           const void* __restrict__ bfe0, u16* __restrict__ z,
                                           const int* __restrict__ mf) {
    int m = mf[0];
    __shared__ __align__(16) u16 fs[64][72];
    int t = threadIdx.x;
    int n0 = blockIdx.x * 64;
    {
        int col = t & 63, rb = t >> 6;
#pragma unroll
        for (int i = 0; i < 16; i++) {
            int row = rb * 16 + i;
            int n = n0 + row;
            fs[row][col] = (n < NN) ? n1l0[n * 64 + col] : (u16)0;
        }
    }
    __syncthreads();
    int lane = t & 63, w = t >> 6, q = lane >> 4, nidx = lane & 15;
    const u16* ar = &fs[w * 16 + nidx][0];
    short8 a0 = *(const short8*)&ar[q * 8];
    short8 a1 = *(const short8*)&ar[32 + q * 8];
#pragma unroll
    for (int jt = 0; jt < 8; jt++) {
        int j = jt * 16 + nidx;
        const u16* wr = Wfe0c + j * 128;
        floatx4 acc = {0.f, 0.f, 0.f, 0.f};
        acc = __builtin_amdgcn_mfma_f32_16x16x32_bf16(a0, *(const short8*)&wr[q * 8], acc, 0, 0, 0);
        acc = __builtin_amdgcn_mfma_f32_16x16x32_bf16(a1, *(const short8*)&wr[32 + q * 8], acc, 0, 0, 0);
        float hb = 0.5f * ldf(bfe0, j, m);
#pragma unroll
        for (int r = 0; r < 4; r++) {
            int row = w * 16 + q * 4 + r;
            int n = n0 + row;
            if (n < NN) z[(size_t)n * 128 + j] = f2bf(acc[r] + hb);
        }
    }
}

// K34: fused node MLP l0 + BN + node encoder l1 -> n1_l1 [50000 x 64] bf16. MFMA, 64 nodes/block.
__global__ __launch_bounds__(256) void k_node_l0(
    const u16* __restrict__ n1l0, const float* __restrict__ sp, const float* __restrict__ sn,
    const void* __restrict__ We0, const u16* __restrict__ Wfn0c, const void* __restrict__ bfn0,
    const void* __restrict__ g0, const void* __restrict__ b0,
    const void* __restrict__ rm0, const void* __restrict__ rv0,
    const u16* __restrict__ Wn1c, u16* __restrict__ n1l1, const int* __restrict__ mf) {
    int m = mf[0];
    __shared__ __align__(16) u16 fs[64][136];
    __shared__ __align__(16) u16 xs[64][136];
    int t = threadIdx.x;
    int n0 = blockIdx.x * 64;
    {   // fs[row][col] = concat(analytic agg_l0, n1_l0), bf16
        int col = t & 127;
        int rbase = t >> 7;              // 0 or 1
        float wp = 0.f, wn = 0.f;
        if (col < 64) { float w0 = ldf(We0, col, m); wp = fmaxf(w0, 0.f); wn = fminf(w0, 0.f); }
#pragma unroll
        for (int i = 0; i < 32; i++) {
            int row = rbase + 2 * i;
            int n = n0 + row;
            float v = 0.f;
            if (n < NN) v = (col < 64) ? (wp * sp[n] + wn * sn[n]) : bfu(n1l0[n * 64 + col - 64]);
            fs[row][col] = f2bf(v);
        }
    }
    __syncthreads();
    int lane = t & 63, w = t >> 6, q = lane >> 4, nidx = lane & 15;
    {
        const u16* ar = &fs[w * 16 + nidx][0];
        short8 a0 = *(const short8*)&ar[q * 8];
        short8 a1 = *(const short8*)&ar[32 + q * 8];
        short8 a2 = *(const short8*)&ar[64 + q * 8];
        short8 a3 = *(const short8*)&ar[96 + q * 8];
#pragma unroll
        for (int jt = 0; jt < 8; jt++) {
            int j = jt * 16 + nidx;
            const u16* wr = Wfn0c + j * 128;
            floatx4 acc = {0.f, 0.f, 0.f, 0.f};
            acc = __builtin_amdgcn_mfma_f32_16x16x32_bf16(a0, *(const short8*)&wr[q * 8], acc, 0, 0, 0);
            acc = __builtin_amdgcn_mfma_f32_16x16x32_bf16(a1, *(const short8*)&wr[32 + q * 8], acc, 0, 0, 0);
            acc = __builtin_amdgcn_mfma_f32_16x16x32_bf16(a2, *(const short8*)&wr[64 + q * 8], acc, 0, 0, 0);
            acc = __builtin_amdgcn_mfma_f32_16x16x32_bf16(a3, *(const short8*)&wr[96 + q * 8], acc, 0, 0, 0);
            float bias = ldf(bfn0, j, m);
            float sc = ldf(g0, j, m) * rsqrtf(ldf(rv0, j, m) + BN_EPS);
            float sh = ldf(b0, j, m) - ldf(rm0, j, m) * sc;
#pragma unroll
            for (int r = 0; r < 4; r++) {
                int row = w * 16 + q * 4 + r;
                xs[row][j] = f2bf(fmaxf(acc[r] + bias, 0.f) * sc + sh);
            }
        }
    }
    __syncthreads();
    {
        const u16* ar = &xs[w * 16 + nidx][0];
        short8 a0 = *(const short8*)&ar[q * 8];
        short8 a1 = *(const short8*)&ar[32 + q * 8];
        short8 a2 = *(const short8*)&ar[64 + q * 8];
        short8 a3 = *(const short8*)&ar[96 + q * 8];
#pragma unroll
        for (int jt = 0; jt < 4; jt++) {
            int j = jt * 16 + nidx;
            const u16* wr = Wn1c + j * 128;
            floatx4 acc = {0.f, 0.f, 0.f, 0.f};
            acc = __builtin_amdgcn_mfma_f32_16x16x32_bf16(a0, *(const short8*)&wr[q * 8], acc, 0, 0, 0);
            acc = __builtin_amdgcn_mfma_f32_16x16x32_bf16(a1, *(const short8*)&wr[32 + q * 8], acc, 0, 0, 0);
            acc = __builtin_amdgcn_mfma_f32_16x16x32_bf16(a2, *(const short8*)&wr[64 + q * 8], acc, 0, 0, 0);
            acc = __builtin_amdgcn_mfma_f32_16x16x32_bf16(a3, *(const short8*)&wr[96 + q * 8], acc, 0, 0, 0);
#pragma unroll
            for (int r = 0; r < 4; r++) {
                int row = w * 16 + q * 4 + r;
                int n = n0 + row;
                if (n < NN) n1l1[n * 64 + j] = f2bf(fmaxf(acc[r], 0.f));
            }
        }
    }
}

// K5v8: GEMM1-free edge pipeline. h1[e] = relu(z[src]+z[dst]+ae*PN) computed
// elementwise — each lane gathers exactly its own 16B k-chunk of z (no cross-wave
// duplication). Then GEMM2 (h1 @ We1^T) + per-edge global atomics as before.
__global__ __launch_bounds__(256) void k_edge8(
    const int* __restrict__ ei, const void* __restrict__ ea, const u16* __restrict__ z,
    const float* __restrict__ PN, const u16* __restrict__ We1c,
    float* __restrict__ agg, const int* __restrict__ mf) {
    int m = mf[0];
    __shared__ __align__(16) u16 h1s[2][16][136];
    int t = threadIdx.x;
    int lane = t & 63, w = t >> 6, q = lane >> 4, nidx = lane & 15;
    int ko = w * 32 + q * 8;                 // this lane's k-chunk of h1 (8 of 128)
    float Pk[8], Nk[8];
#pragma unroll
    for (int j = 0; j < 8; j++) { Pk[j] = PN[ko + j]; Nk[j] = PN[128 + ko + j]; }
    int c2 = w * 16 + nidx;
    const u16* wr2 = We1c + c2 * 128;
    short8 wB0 = *(const short8*)&wr2[q * 8];
    short8 wB1 = *(const short8*)&wr2[32 + q * 8];
    short8 wB2 = *(const short8*)&wr2[64 + q * 8];
    short8 wB3 = *(const short8*)&wr2[96 + q * 8];

    int e0 = blockIdx.x * (16 * TPB);
    // prologue: tile 0 meta + z gathers
    int eb = e0 + nidx;
    int sv = ei[eb];
    int dv = ei[NE + eb];
    float av = ldf(ea, eb, m);
    short8 gzs = *(const short8*)&z[(size_t)sv * 128 + ko];
    short8 gzd = *(const short8*)&z[(size_t)dv * 128 + ko];

    for (int tile = 0; tile < TPB; tile++) {
        short8 czs = gzs, czd = gzd;
        int curd = dv;
        float cura = av;
        if (tile + 1 < TPB) {   // next tile's meta + gathers (hidden under this tile)
            int en = e0 + (tile + 1) * 16 + nidx;
            sv = ei[en];
            dv = ei[NE + en];
            av = ldf(ea, en, m);
            gzs = *(const short8*)&z[(size_t)sv * 128 + ko];
            gzd = *(const short8*)&z[(size_t)dv * 128 + ko];
        }
        // h1 chunk: elementwise z[s]+z[d]+ae*PN, relu, pack
        float pf = fmaxf(cura, 0.f), nf = fminf(cura, 0.f);
        short8 hp;
#pragma unroll
        for (int j = 0; j < 8; j++) {
            float v = bfu((u16)czs[j]) + bfu((u16)czd[j]) + pf * Pk[j] + nf * Nk[j];
            hp[j] = (short)f2bf(fmaxf(v, 0.f));
        }
        *(short8*)&h1s[tile & 1][nidx][ko] = hp;
        LDS_BARRIER();
        // GEMM2: e1' = relu(h1 @ We1^T); D row=q*4+r=edge, col=nidx -> channel c2
        const u16* arow = &h1s[tile & 1][nidx][0];
        floatx4 accA = {0.f, 0.f, 0.f, 0.f};
        floatx4 accB = {0.f, 0.f, 0.f, 0.f};
        accA = __builtin_amdgcn_mfma_f32_16x16x32_bf16(*(const short8*)&arow[q * 8], wB0, accA, 0, 0, 0);
        accB = __builtin_amdgcn_mfma_f32_16x16x32_bf16(*(const short8*)&arow[32 + q * 8], wB1, accB, 0, 0, 0);
        accA = __builtin_amdgcn_mfma_f32_16x16x32_bf16(*(const short8*)&arow[64 + q * 8], wB2, accA, 0, 0, 0);
        accB = __builtin_amdgcn_mfma_f32_16x16x32_bf16(*(const short8*)&arow[96 + q * 8], wB3, accB, 0, 0, 0);
        int d0 = __shfl(curd, q * 4 + 0);
        int d1 = __shfl(curd, q * 4 + 1);
        int d2 = __shfl(curd, q * 4 + 2);
        int d3 = __shfl(curd, q * 4 + 3);
        atomicAdd(agg + (size_t)d0 * 64 + c2, fmaxf(accA[0] + accB[0], 0.f));
        atomicAdd(agg + (size_t)d1 * 64 + c2, fmaxf(accA[1] + accB[1], 0.f));
        atomicAdd(agg + (size_t)d2 * 64 + c2, fmaxf(accA[2] + accB[2], 0.f));
        atomicAdd(agg + (size_t)d3 * 64 + c2, fmaxf(accA[3] + accB[3], 0.f));
        // double-buffered h1s + LDS_BARRIER order write(t+1) vs read(t)
    }
}

// K6: node MLP l1 + BN -> d_out. MFMA, 64 nodes/block.
__global__ __launch_bounds__(256) void k_node_l1(
    const u16* __restrict__ n1l1, const float* __restrict__ agg,
    const u16* __restrict__ Wfn1c, const void* __restrict__ bfn1,
    const void* __restrict__ g1, const void* __restrict__ b1,
    const void* __restrict__ rm1, const void* __restrict__ rv1,
    void* __restrict__ out, const int* __restrict__ mf) {
    int m = mf[0];
    __shared__ __align__(16) u16 fs[64][136];
    int t = threadIdx.x;
    int n0 = blockIdx.x * 64;
    {
        int col = t & 127;
        int rbase = t >> 7;
#pragma unroll
        for (int i = 0; i < 32; i++) {
            int row = rbase + 2 * i;
            int n = n0 + row;
            float v = 0.f;
            if (n < NN) v = (col < 64) ? agg[n * 64 + col] : bfu(n1l1[n * 64 + col - 64]);
            fs[row][col] = f2bf(v);
        }
    }
    __syncthreads();
    int lane = t & 63, w = t >> 6, q = lane >> 4, nidx = lane & 15;
    const u16* ar = &fs[w * 16 + nidx][0];
    short8 a0 = *(const short8*)&ar[q * 8];
    short8 a1 = *(const short8*)&ar[32 + q * 8];
    short8 a2 = *(const short8*)&ar[64 + q * 8];
    short8 a3 = *(const short8*)&ar[96 + q * 8];
#pragma unroll
    for (int jt = 0; jt < 8; jt++) {
        int j = jt * 16 + nidx;
        const u16* wr = Wfn1c + j * 128;
        floatx4 acc = {0.f, 0.f, 0.f, 0.f};
        acc = __builtin_amdgcn_mfma_f32_16x16x32_bf16(a0, *(const short8*)&wr[q * 8], acc, 0, 0, 0);
        acc = __builtin_amdgcn_mfma_f32_16x16x32_bf16(a1, *(const short8*)&wr[32 + q * 8], acc, 0, 0, 0);
        acc = __builtin_amdgcn_mfma_f32_16x16x32_bf16(a2, *(const short8*)&wr[64 + q * 8], acc, 0, 0, 0);
        acc = __builtin_amdgcn_mfma_f32_16x16x32_bf16(a3, *(const short8*)&wr[96 + q * 8], acc, 0, 0, 0);
        float bias = ldf(bfn1, j, m);
        float sc = ldf(g1, j, m) * rsqrtf(ldf(rv1, j, m) + BN_EPS);
        float sh = ldf(b1, j, m) - ldf(rm1, j, m) * sc;
#pragma unroll
        for (int r = 0; r < 4; r++) {
            int row = w * 16 + q * 4 + r;
            int n = n0 + row;
            if (n < NN) {
                float v = fmaxf(acc[r] + bias, 0.f) * sc + sh;
                if (m) ((float*)out)[n * 128 + j] = v;
                else   ((u16*)out)[n * 128 + j] = f2bf(v);
            }
        }
    }
}

extern "C" void kernel_launch(void* const* d_in, const int* in_sizes, int n_in,
                              void* d_out, int out_size, void* d_ws, size_t ws_size,
                              hipStream_t stream) {
    const void* x    = d_in[0];
    const void* ea   = d_in[1];
    const int*  ei   = (const int*)d_in[2];
    const void* Wn0  = d_in[3];
    const void* We0  = d_in[4];
    const void* Wfn0 = d_in[5];
    const void* bfn0 = d_in[6];
    const void* Wfe0 = d_in[7];
    const void* bfe0 = d_in[8];
    const void* g0   = d_in[9];
    const void* b0   = d_in[10];
    const void* rm0  = d_in[11];
    const void* rv0  = d_in[12];
    const void* Wn1  = d_in[13];
    const void* We1  = d_in[14];
    const void* Wfn1 = d_in[15];
    const void* bfn1 = d_in[16];
    // d_in[17]/d_in[18] (l1_Wfe/l1_bfe): dead — layer-1 edge output discarded
    const void* g1   = d_in[19];
    const void* b1   = d_in[20];
    const void* rm1  = d_in[21];
    const void* rv1  = d_in[22];

    float* wsf    = (float*)d_ws;
    float* agg    = wsf;                          // 3,200,000 f32
    u16*   n1l0   = (u16*)(wsf + 3200000);        // 3.2M u16
    u16*   n1l1   = (u16*)(wsf + 4800000);        // 3.2M u16
    float* sp     = wsf + 6400000;                // 50,000
    float* sn     = wsf + 6450000;                // 50,000
    float* PN     = wsf + 6500000;                // 256
    u16*   Wc     = (u16*)(wsf + 6500256);        // 65,536 u16 canonical weights
    int*   mode   = (int*)(wsf + 6533024);        // 1
    u16*   z      = (u16*)(wsf + 6533028);        // 50,000 x 128 bf16 (12.8 MB)
    u16* Wfe0c = Wc;
    u16* We1c  = Wc + 16384;
    u16* Wfn0c = Wc + 24576;
    u16* Wn1c  = Wc + 40960;
    u16* Wfn1c = Wc + 49152;

    // Zero sp + sn (contiguous) and agg (atomic-accumulated).
    hipMemsetAsync(sp, 0, 100000 * sizeof(float), stream);
    hipMemsetAsync(agg, 0, 3200000 * sizeof(float), stream);

    k_cvtw<<<257, 256, 0, stream>>>((const u16*)x, Wfe0, We1, Wfn0, Wn1, Wfn1,
                                    We0, Wc, PN, mode);
    k_enc0h<<<9375, 256, 0, stream>>>(x, Wn0, n1l0, ei, ea, sp, sn, mode);
    k_z<<<782, 256, 0, stream>>>(n1l0, Wfe0c, bfe0, z, mode);
    k_node_l0<<<782, 256, 0, stream>>>(n1l0, sp, sn, We0, Wfn0c, bfn0,
                                       g0, b0, rm0, rv0, Wn1c, n1l1, mode);
    k_edge8<<<NE / (16 * TPB), 256, 0, stream>>>(ei, ea, z, PN, We1c, agg, mode);
    k_node_l1<<<782, 256, 0, stream>>>(n1l1, agg, Wfn1c, bfn1,
                                       g1, b1, rm1, rv1, d_out, mode);
}

// Round 9
// 620.051 us; speedup vs baseline: 1.0010x; 1.0010x over previous
//
#include <hip/hip_runtime.h>

typedef unsigned short u16;
typedef __attribute__((ext_vector_type(8))) short short8;
typedef __attribute__((ext_vector_type(4))) float floatx4;

#define NN 50000
#define NE 1600000
#define BN_EPS 1e-5f
#define TPB 8                 // 16-edge tiles per k_edge9 block

// LDS-only barrier: drains lgkmcnt (DS ops) but NOT vmcnt.
#define LDS_BARRIER() asm volatile("s_waitcnt lgkmcnt(0)\n\ts_barrier" ::: "memory")

__device__ __forceinline__ float bfu(u16 u) {
    union { unsigned u32; float f; } v; v.u32 = ((unsigned)u) << 16; return v.f;
}
__device__ __forceinline__ u16 f2bf(float f) {
    union { float f; unsigned u; } v; v.f = f;
    unsigned r = v.u + 0x7FFFu + ((v.u >> 16) & 1u);
    return (u16)(r >> 16);
}
// mode m: 1 = buffers hold float32, 0 = buffers hold bf16
__device__ __forceinline__ float ldf(const void* p, int i, int m) {
    return m ? ((const float*)p)[i] : bfu(((const u16*)p)[i]);
}

// K0b: canonicalize all MFMA-consumed weights to bf16 ws copies, with INLINE dtype
// detection (every block recomputes mode from x; block 0 publishes it). Block 256
// computes the PN rank-1 vectors instead of converting weights.
// Layout in dst: Wfe0[16384] | We1[8192] | Wfn0[16384] | Wn1[8192] | Wfn1[16384]
__global__ __launch_bounds__(256) void k_cvtw(const u16* __restrict__ x,
                                              const void* __restrict__ W0, const void* __restrict__ W1,
                                              const void* __restrict__ W2, const void* __restrict__ W3,
                                              const void* __restrict__ W4,
                                              const void* __restrict__ We0raw,
                                              u16* __restrict__ dst, float* __restrict__ PN,
                                              int* __restrict__ mode) {
    int t = threadIdx.x;
    __shared__ float sred[4];
    float mx = 0.f;
    for (int i = t; i < 4096; i += 256) mx = fmaxf(mx, fabsf(bfu(x[i])));
#pragma unroll
    for (int o = 32; o > 0; o >>= 1) mx = fmaxf(mx, __shfl_down(mx, o));
    if ((t & 63) == 0) sred[t >> 6] = mx;
    __syncthreads();
    float m2 = fmaxf(fmaxf(sred[0], sred[1]), fmaxf(sred[2], sred[3]));
    int m = (m2 > 1e4f) ? 1 : 0;
    if (blockIdx.x == 0 && t == 0) mode[0] = m;
    if (blockIdx.x == 256) {   // PN block: P[j]/N[j] from raw We0 + raw Wfe0 (W0)
        if (t < 128) {
            float p = 0.f, n = 0.f;
            for (int k = 0; k < 64; k++) {
                float w = ldf(We0raw, k, m);
                float wf = ldf(W0, t * 128 + 64 + k, m);
                p += fmaxf(w, 0.f) * wf;
                n += fminf(w, 0.f) * wf;
            }
            PN[t] = p; PN[128 + t] = n;
        }
        return;
    }
    int i = blockIdx.x * 256 + t;   // 65536 total
    const void* src; int off;
    if (i < 16384)      { src = W0; off = i; }
    else if (i < 24576) { src = W1; off = i - 16384; }
    else if (i < 40960) { src = W2; off = i - 24576; }
    else if (i < 49152) { src = W3; off = i - 40960; }
    else                { src = W4; off = i - 49152; }
    dst[i] = m ? f2bf(((const float*)src)[off]) : ((const u16*)src)[off];
}

// K1h: fused {node encoder l0 (16 nodes/block)} + {per-node +/- edge_attr sums} via block split.
__global__ __launch_bounds__(256) void k_enc0h(const void* __restrict__ x, const void* __restrict__ Wn,
                                               u16* __restrict__ n1, const int* __restrict__ ei,
                                               const void* __restrict__ ea,
                                               float* __restrict__ sp, float* __restrict__ sn,
                                               const int* __restrict__ mf) {
    int b = blockIdx.x;
    int t = threadIdx.x;
    int m = mf[0];
    if (b >= 3125) {   // esum part: 6250 blocks
        int e = (b - 3125) * 256 + t;
        float a = ldf(ea, e, m);
        int d = ei[NE + e];
        if (a > 0.f) atomicAdd(sp + d, a);
        else if (a < 0.f) atomicAdd(sn + d, a);
        return;
    }
    __shared__ float Wns[64 * 17];
    __shared__ float xsh[16][17];
    int n0 = b * 16;
    for (int i = t; i < 1024; i += 256) Wns[(i >> 4) * 17 + (i & 15)] = ldf(Wn, i, m);
    xsh[t >> 4][t & 15] = ldf(x, n0 * 16 + t, m);
    __syncthreads();
    int c = t & 63, ng = t >> 6;   // ng: node group 0..3, nodes ng*4..ng*4+3
    float a0 = 0.f, a1 = 0.f, a2 = 0.f, a3 = 0.f;
#pragma unroll
    for (int k = 0; k < 16; k++) {
        float wv = Wns[c * 17 + k];
        a0 += xsh[ng * 4 + 0][k] * wv;
        a1 += xsh[ng * 4 + 1][k] * wv;
        a2 += xsh[ng * 4 + 2][k] * wv;
        a3 += xsh[ng * 4 + 3][k] * wv;
    }
    n1[(n0 + ng * 4 + 0) * 64 + c] = f2bf(fmaxf(a0, 0.f));
    n1[(n0 + ng * 4 + 1) * 64 + c] = f2bf(fmaxf(a1, 0.f));
    n1[(n0 + ng * 4 + 2) * 64 + c] = f2bf(fmaxf(a2, 0.f));
    n1[(n0 + ng * 4 + 3) * 64 + c] = f2bf(fmaxf(a3, 0.f));
}

// K_Z: per-node edge-MLP precompute. z[n][j] = sum_k n1l0[n][k]*Wfe0[j][k] + 0.5*bfe0[j]
// (j=0..127; Wfe0 cols 0..63 = node part). Then for any edge: h1 = relu(z[s]+z[d]+ae*PN).
__global__ __launch_bounds__(256) void k_z(const u16* __restrict__ n1l0, const u16* __restrict__ Wfe0c,
                                           const void* __restrict__ bfe0, u16* __restrict__ z,
                                           const int* __restrict__ mf) {
    int m = mf[0];
    __shared__ __align__(16) u16 fs[64][72];
    int t = threadIdx.x;
    int n0 = blockIdx.x * 64;
    {
        int col = t & 63, rb = t >> 6;
#pragma unroll
        for (int i = 0; i < 16; i++) {
            int row = rb * 16 + i;
            int n = n0 + row;
            fs[row][col] = (n < NN) ? n1l0[n * 64 + col] : (u16)0;
        }
    }
    __syncthreads();
    int lane = t & 63, w = t >> 6, q = lane >> 4, nidx = lane & 15;
    const u16* ar = &fs[w * 16 + nidx][0];
    short8 a0 = *(const short8*)&ar[q * 8];
    short8 a1 = *(const short8*)&ar[32 + q * 8];
#pragma unroll
    for (int jt = 0; jt < 8; jt++) {
        int j = jt * 16 + nidx;
        const u16* wr = Wfe0c + j * 128;
        floatx4 acc = {0.f, 0.f, 0.f, 0.f};
        acc = __builtin_amdgcn_mfma_f32_16x16x32_bf16(a0, *(const short8*)&wr[q * 8], acc, 0, 0, 0);
        acc = __builtin_amdgcn_mfma_f32_16x16x32_bf16(a1, *(const short8*)&wr[32 + q * 8], acc, 0, 0, 0);
        float hb = 0.5f * ldf(bfe0, j, m);
#pragma unroll
        for (int r = 0; r < 4; r++) {
            int row = w * 16 + q * 4 + r;
            int n = n0 + row;
            if (n < NN) z[(size_t)n * 128 + j] = f2bf(acc[r] + hb);
        }
    }
}

// K34: fused node MLP l0 + BN + node encoder l1 -> n1_l1 [50000 x 64] bf16. MFMA, 64 nodes/block.
__global__ __launch_bounds__(256) void k_node_l0(
    const u16* __restrict__ n1l0, const float* __restrict__ sp, const float* __restrict__ sn,
    const void* __restrict__ We0, const u16* __restrict__ Wfn0c, const void* __restrict__ bfn0,
    const void* __restrict__ g0, const void* __restrict__ b0,
    const void* __restrict__ rm0, const void* __restrict__ rv0,
    const u16* __restrict__ Wn1c, u16* __restrict__ n1l1, const int* __restrict__ mf) {
    int m = mf[0];
    __shared__ __align__(16) u16 fs[64][136];
    __shared__ __align__(16) u16 xs[64][136];
    int t = threadIdx.x;
    int n0 = blockIdx.x * 64;
    {   // fs[row][col] = concat(analytic agg_l0, n1_l0), bf16
        int col = t & 127;
        int rbase = t >> 7;              // 0 or 1
        float wp = 0.f, wn = 0.f;
        if (col < 64) { float w0 = ldf(We0, col, m); wp = fmaxf(w0, 0.f); wn = fminf(w0, 0.f); }
#pragma unroll
        for (int i = 0; i < 32; i++) {
            int row = rbase + 2 * i;
            int n = n0 + row;
            float v = 0.f;
            if (n < NN) v = (col < 64) ? (wp * sp[n] + wn * sn[n]) : bfu(n1l0[n * 64 + col - 64]);
            fs[row][col] = f2bf(v);
        }
    }
    __syncthreads();
    int lane = t & 63, w = t >> 6, q = lane >> 4, nidx = lane & 15;
    {
        const u16* ar = &fs[w * 16 + nidx][0];
        short8 a0 = *(const short8*)&ar[q * 8];
        short8 a1 = *(const short8*)&ar[32 + q * 8];
        short8 a2 = *(const short8*)&ar[64 + q * 8];
        short8 a3 = *(const short8*)&ar[96 + q * 8];
#pragma unroll
        for (int jt = 0; jt < 8; jt++) {
            int j = jt * 16 + nidx;
            const u16* wr = Wfn0c + j * 128;
            floatx4 acc = {0.f, 0.f, 0.f, 0.f};
            acc = __builtin_amdgcn_mfma_f32_16x16x32_bf16(a0, *(const short8*)&wr[q * 8], acc, 0, 0, 0);
            acc = __builtin_amdgcn_mfma_f32_16x16x32_bf16(a1, *(const short8*)&wr[32 + q * 8], acc, 0, 0, 0);
            acc = __builtin_amdgcn_mfma_f32_16x16x32_bf16(a2, *(const short8*)&wr[64 + q * 8], acc, 0, 0, 0);
            acc = __builtin_amdgcn_mfma_f32_16x16x32_bf16(a3, *(const short8*)&wr[96 + q * 8], acc, 0, 0, 0);
            float bias = ldf(bfn0, j, m);
            float sc = ldf(g0, j, m) * rsqrtf(ldf(rv0, j, m) + BN_EPS);
            float sh = ldf(b0, j, m) - ldf(rm0, j, m) * sc;
#pragma unroll
            for (int r = 0; r < 4; r++) {
                int row = w * 16 + q * 4 + r;
                xs[row][j] = f2bf(fmaxf(acc[r] + bias, 0.f) * sc + sh);
            }
        }
    }
    __syncthreads();
    {
        const u16* ar = &xs[w * 16 + nidx][0];
        short8 a0 = *(const short8*)&ar[q * 8];
        short8 a1 = *(const short8*)&ar[32 + q * 8];
        short8 a2 = *(const short8*)&ar[64 + q * 8];
        short8 a3 = *(const short8*)&ar[96 + q * 8];
#pragma unroll
        for (int jt = 0; jt < 4; jt++) {
            int j = jt * 16 + nidx;
            const u16* wr = Wn1c + j * 128;
            floatx4 acc = {0.f, 0.f, 0.f, 0.f};
            acc = __builtin_amdgcn_mfma_f32_16x16x32_bf16(a0, *(const short8*)&wr[q * 8], acc, 0, 0, 0);
            acc = __builtin_amdgcn_mfma_f32_16x16x32_bf16(a1, *(const short8*)&wr[32 + q * 8], acc, 0, 0, 0);
            acc = __builtin_amdgcn_mfma_f32_16x16x32_bf16(a2, *(const short8*)&wr[64 + q * 8], acc, 0, 0, 0);
            acc = __builtin_amdgcn_mfma_f32_16x16x32_bf16(a3, *(const short8*)&wr[96 + q * 8], acc, 0, 0, 0);
#pragma unroll
            for (int r = 0; r < 4; r++) {
                int row = w * 16 + q * 4 + r;
                int n = n0 + row;
                if (n < NN) n1l1[n * 64 + j] = f2bf(fmaxf(acc[r], 0.f));
            }
        }
    }
}

// K5v9: GEMM1-free edge pipeline with DECOUPLED prefetch. All TPB tiles' edge meta
// (src|dst packed, ea) loaded in the block prologue (independent loads, latency paid
// once). z-gathers run a 2-deep pipeline: tile t consumes slot[t&1] and immediately
// refills it for tile t+2 — each gather has ~2 compute windows to land instead of
// being serialized behind its meta load inside one window.
__global__ __launch_bounds__(256) void k_edge9(
    const int* __restrict__ ei, const void* __restrict__ ea, const u16* __restrict__ z,
    const float* __restrict__ PN, const u16* __restrict__ We1c,
    float* __restrict__ agg, const int* __restrict__ mf) {
    int m = mf[0];
    __shared__ __align__(16) u16 h1s[2][16][136];
    int t = threadIdx.x;
    int lane = t & 63, w = t >> 6, q = lane >> 4, nidx = lane & 15;
    int ko = w * 32 + q * 8;                 // this lane's k-chunk of h1 (8 of 128)
    float Pk[8], Nk[8];
#pragma unroll
    for (int j = 0; j < 8; j++) { Pk[j] = PN[ko + j]; Nk[j] = PN[128 + ko + j]; }
    int c2 = w * 16 + nidx;
    const u16* wr2 = We1c + c2 * 128;
    short8 wB0 = *(const short8*)&wr2[q * 8];
    short8 wB1 = *(const short8*)&wr2[32 + q * 8];
    short8 wB2 = *(const short8*)&wr2[64 + q * 8];
    short8 wB3 = *(const short8*)&wr2[96 + q * 8];

    int e0 = blockIdx.x * (16 * TPB);
    // ---- prologue: ALL tile meta upfront (independent loads, one latency) ----
    unsigned pk[TPB];
    float av[TPB];
#pragma unroll
    for (int tl = 0; tl < TPB; tl++) {
        int en = e0 + tl * 16 + nidx;
        unsigned s = (unsigned)ei[en];
        unsigned d = (unsigned)ei[NE + en];
        pk[tl] = s | (d << 16);
        av[tl] = ldf(ea, en, m);
    }
    // ---- 2-deep z-gather pipeline: slots for tiles t, t+1 ----
    short8 zsb[2], zdb[2];
#pragma unroll
    for (int tl = 0; tl < 2; tl++) {
        unsigned s = pk[tl] & 0xFFFFu, d = pk[tl] >> 16;
        zsb[tl] = *(const short8*)&z[(size_t)s * 128 + ko];
        zdb[tl] = *(const short8*)&z[(size_t)d * 128 + ko];
    }

#pragma unroll
    for (int tile = 0; tile < TPB; tile++) {
        short8 czs = zsb[tile & 1], czd = zdb[tile & 1];
        if (tile + 2 < TPB) {   // refill just-freed slot for tile+2 (2 windows to land)
            unsigned s = pk[tile + 2] & 0xFFFFu, d = pk[tile + 2] >> 16;
            zsb[tile & 1] = *(const short8*)&z[(size_t)s * 128 + ko];
            zdb[tile & 1] = *(const short8*)&z[(size_t)d * 128 + ko];
        }
        // h1 chunk: elementwise z[s]+z[d]+ae*PN, relu, pack
        float cura = av[tile];
        float pf = fmaxf(cura, 0.f), nf = fminf(cura, 0.f);
        short8 hp;
#pragma unroll
        for (int j = 0; j < 8; j++) {
            float v = bfu((u16)czs[j]) + bfu((u16)czd[j]) + pf * Pk[j] + nf * Nk[j];
            hp[j] = (short)f2bf(fmaxf(v, 0.f));
        }
        *(short8*)&h1s[tile & 1][nidx][ko] = hp;
        LDS_BARRIER();
        // GEMM2: e1' = relu(h1 @ We1^T); D row=q*4+r=edge, col=nidx -> channel c2
        const u16* arow = &h1s[tile & 1][nidx][0];
        floatx4 accA = {0.f, 0.f, 0.f, 0.f};
        floatx4 accB = {0.f, 0.f, 0.f, 0.f};
        accA = __builtin_amdgcn_mfma_f32_16x16x32_bf16(*(const short8*)&arow[q * 8], wB0, accA, 0, 0, 0);
        accB = __builtin_amdgcn_mfma_f32_16x16x32_bf16(*(const short8*)&arow[32 + q * 8], wB1, accB, 0, 0, 0);
        accA = __builtin_amdgcn_mfma_f32_16x16x32_bf16(*(const short8*)&arow[64 + q * 8], wB2, accA, 0, 0, 0);
        accB = __builtin_amdgcn_mfma_f32_16x16x32_bf16(*(const short8*)&arow[96 + q * 8], wB3, accB, 0, 0, 0);
        int pkt = (int)pk[tile];
        unsigned x0 = (unsigned)__shfl(pkt, q * 4 + 0);
        unsigned x1 = (unsigned)__shfl(pkt, q * 4 + 1);
        unsigned x2 = (unsigned)__shfl(pkt, q * 4 + 2);
        unsigned x3 = (unsigned)__shfl(pkt, q * 4 + 3);
        atomicAdd(agg + (size_t)(x0 >> 16) * 64 + c2, fmaxf(accA[0] + accB[0], 0.f));
        atomicAdd(agg + (size_t)(x1 >> 16) * 64 + c2, fmaxf(accA[1] + accB[1], 0.f));
        atomicAdd(agg + (size_t)(x2 >> 16) * 64 + c2, fmaxf(accA[2] + accB[2], 0.f));
        atomicAdd(agg + (size_t)(x3 >> 16) * 64 + c2, fmaxf(accA[3] + accB[3], 0.f));
        // double-buffered h1s + LDS_BARRIER order write(t+1) vs read(t)
    }
}

// K6: node MLP l1 + BN -> d_out. MFMA, 64 nodes/block.
__global__ __launch_bounds__(256) void k_node_l1(
    const u16* __restrict__ n1l1, const float* __restrict__ agg,
    const u16* __restrict__ Wfn1c, const void* __restrict__ bfn1,
    const void* __restrict__ g1, const void* __restrict__ b1,
    const void* __restrict__ rm1, const void* __restrict__ rv1,
    void* __restrict__ out, const int* __restrict__ mf) {
    int m = mf[0];
    __shared__ __align__(16) u16 fs[64][136];
    int t = threadIdx.x;
    int n0 = blockIdx.x * 64;
    {
        int col = t & 127;
        int rbase = t >> 7;
#pragma unroll
        for (int i = 0; i < 32; i++) {
            int row = rbase + 2 * i;
            int n = n0 + row;
            float v = 0.f;
            if (n < NN) v = (col < 64) ? agg[n * 64 + col] : bfu(n1l1[n * 64 + col - 64]);
            fs[row][col] = f2bf(v);
        }
    }
    __syncthreads();
    int lane = t & 63, w = t >> 6, q = lane >> 4, nidx = lane & 15;
    const u16* ar = &fs[w * 16 + nidx][0];
    short8 a0 = *(const short8*)&ar[q * 8];
    short8 a1 = *(const short8*)&ar[32 + q * 8];
    short8 a2 = *(const short8*)&ar[64 + q * 8];
    short8 a3 = *(const short8*)&ar[96 + q * 8];
#pragma unroll
    for (int jt = 0; jt < 8; jt++) {
        int j = jt * 16 + nidx;
        const u16* wr = Wfn1c + j * 128;
        floatx4 acc = {0.f, 0.f, 0.f, 0.f};
        acc = __builtin_amdgcn_mfma_f32_16x16x32_bf16(a0, *(const short8*)&wr[q * 8], acc, 0, 0, 0);
        acc = __builtin_amdgcn_mfma_f32_16x16x32_bf16(a1, *(const short8*)&wr[32 + q * 8], acc, 0, 0, 0);
        acc = __builtin_amdgcn_mfma_f32_16x16x32_bf16(a2, *(const short8*)&wr[64 + q * 8], acc, 0, 0, 0);
        acc = __builtin_amdgcn_mfma_f32_16x16x32_bf16(a3, *(const short8*)&wr[96 + q * 8], acc, 0, 0, 0);
        float bias = ldf(bfn1, j, m);
        float sc = ldf(g1, j, m) * rsqrtf(ldf(rv1, j, m) + BN_EPS);
        float sh = ldf(b1, j, m) - ldf(rm1, j, m) * sc;
#pragma unroll
        for (int r = 0; r < 4; r++) {
            int row = w * 16 + q * 4 + r;
            int n = n0 + row;
            if (n < NN) {
                float v = fmaxf(acc[r] + bias, 0.f) * sc + sh;
                if (m) ((float*)out)[n * 128 + j] = v;
                else   ((u16*)out)[n * 128 + j] = f2bf(v);
            }
        }
    }
}

extern "C" void kernel_launch(void* const* d_in, const int* in_sizes, int n_in,
                              void* d_out, int out_size, void* d_ws, size_t ws_size,
                              hipStream_t stream) {
    const void* x    = d_in[0];
    const void* ea   = d_in[1];
    const int*  ei   = (const int*)d_in[2];
    const void* Wn0  = d_in[3];
    const void* We0  = d_in[4];
    const void* Wfn0 = d_in[5];
    const void* bfn0 = d_in[6];
    const void* Wfe0 = d_in[7];
    const void* bfe0 = d_in[8];
    const void* g0   = d_in[9];
    const void* b0   = d_in[10];
    const void* rm0  = d_in[11];
    const void* rv0  = d_in[12];
    const void* Wn1  = d_in[13];
    const void* We1  = d_in[14];
    const void* Wfn1 = d_in[15];
    const void* bfn1 = d_in[16];
    // d_in[17]/d_in[18] (l1_Wfe/l1_bfe): dead — layer-1 edge output discarded
    const void* g1   = d_in[19];
    const void* b1   = d_in[20];
    const void* rm1  = d_in[21];
    const void* rv1  = d_in[22];

    float* wsf    = (float*)d_ws;
    float* agg    = wsf;                          // 3,200,000 f32
    u16*   n1l0   = (u16*)(wsf + 3200000);        // 3.2M u16
    u16*   n1l1   = (u16*)(wsf + 4800000);        // 3.2M u16
    float* sp     = wsf + 6400000;                // 50,000
    float* sn     = wsf + 6450000;                // 50,000
    float* PN     = wsf + 6500000;                // 256
    u16*   Wc     = (u16*)(wsf + 6500256);        // 65,536 u16 canonical weights
    int*   mode   = (int*)(wsf + 6533024);        // 1
    u16*   z      = (u16*)(wsf + 6533028);        // 50,000 x 128 bf16 (12.8 MB)
    u16* Wfe0c = Wc;
    u16* We1c  = Wc + 16384;
    u16* Wfn0c = Wc + 24576;
    u16* Wn1c  = Wc + 40960;
    u16* Wfn1c = Wc + 49152;

    // Zero sp + sn (contiguous) and agg (atomic-accumulated).
    hipMemsetAsync(sp, 0, 100000 * sizeof(float), stream);
    hipMemsetAsync(agg, 0, 3200000 * sizeof(float), stream);

    k_cvtw<<<257, 256, 0, stream>>>((const u16*)x, Wfe0, We1, Wfn0, Wn1, Wfn1,
                                    We0, Wc, PN, mode);
    k_enc0h<<<9375, 256, 0, stream>>>(x, Wn0, n1l0, ei, ea, sp, sn, mode);
    k_z<<<782, 256, 0, stream>>>(n1l0, Wfe0c, bfe0, z, mode);
    k_node_l0<<<782, 256, 0, stream>>>(n1l0, sp, sn, We0, Wfn0c, bfn0,
                                       g0, b0, rm0, rv0, Wn1c, n1l1, mode);
    k_edge9<<<NE / (16 * TPB), 256, 0, stream>>>(ei, ea, z, PN, We1c, agg, mode);
    k_node_l1<<<782, 256, 0, stream>>>(n1l1, agg, Wfn1c, bfn1,
                                       g1, b1, rm1, rv1, d_out, mode);
}